// Round 4
// baseline (68.301 us; speedup 1.0000x reference)
//
#include <hip/hip_runtime.h>
#include <math.h>

// Problem constants (from reference)
#define FH 64    // feature map H (axis indexed by x)
#define FW 64    // feature map W (axis indexed by y)
#define FC 256   // channels
#define PP 7     // pool output dim
#define NROI 256
#define CH 12    // loads in flight per chunk (one round covers most windows)

// One 64-lane wave per output cell (r,i,j). Window walked linearly with
// wave-uniform counters in unrolled chunks of CH independent loads.
// Input domain (0<=x1<x2<=1, 0<=y1<y2<=1) guarantees:
//   lo >= 0, hi = ceil(x2*64) <= 64, and every visited coord
//   xs+sx <= hi-1 <= 63  -> reference's clip() is provably a no-op, dropped.
// Addressing is a single running pointer advanced by cndmask-selected delta
// (next pixel in row, or wrap to next feature row) — no per-slot rebuild.
// Tail slots of the last chunk re-load the final valid pixel (duplicate
// under max = no-op). lane = 4-channel group, 1KB coalesced per load.
__global__ __launch_bounds__(256) void roi_pool_kernel(
        const float* __restrict__ feat,   // (FH, FW, FC)
        const float* __restrict__ rois,   // (NROI, 4): x1,y1,x2,y2
        float* __restrict__ out)          // (NROI, PP, PP, FC)
{
    int gtid = blockIdx.x * blockDim.x + threadIdx.x;
    int lane = gtid & 63;          // 4 channels per lane (float4)
    int cell = gtid >> 6;          // (r, i, j), grid sized exactly

    int j = cell % PP;
    int t = cell / PP;
    int i = t % PP;
    int r = t / PP;

    float4 roi = ((const float4*)rois)[r];   // x1,y1,x2,y2 in one 16B load

    int xlo = (int)floorf(roi.x * (float)FH);
    int xspan = (int)ceilf(roi.z * (float)FH) - xlo;
    xspan = xspan > 1 ? xspan : 1;
    int ylo = (int)floorf(roi.y * (float)FW);
    int yspan = (int)ceilf(roi.w * (float)FW) - ylo;
    yspan = yspan > 1 ? yspan : 1;

    // bin bounds (exact reference math; nonneg -> int div == floor)
    int xs = xlo + (i * xspan) / PP;
    int xe = xlo + ((i + 1) * xspan + (PP - 1)) / PP;
    int xlen = xe - xs; xlen = xlen > 1 ? xlen : 1;
    int ys = ylo + (j * yspan) / PP;
    int ye = ylo + ((j + 1) * yspan + (PP - 1)) / PP;
    int ylen = ye - ys; ylen = ylen > 1 ? ylen : 1;

    const float4* __restrict__ p =
        (const float4*)feat + (size_t)(xs * FW + ys) * (FC / 4) + lane;
    const int dnext = (FC / 4);                       // +1 pixel in y
    const int dwrap = (FW - ylen + 1) * (FC / 4);     // wrap to next x row

    float4 acc = make_float4(-INFINITY, -INFINITY, -INFINITY, -INFINITY);

    const int n = xlen * ylen;     // wave-uniform window size (<= 36 here)
    int sy = 0;                    // position within current y-run

    for (int q = 0; q < n; q += CH) {
        float4 v[CH];
#pragma unroll
        for (int u = 0; u < CH; ++u) {
            v[u] = *p;
            if (q + u + 1 < n) {                  // advance while valid
                int wrap = (sy + 1 == ylen);
                p += wrap ? dwrap : dnext;
                sy = wrap ? 0 : sy + 1;
            }
        }
#pragma unroll
        for (int u = 0; u < CH; ++u) {
            acc.x = fmaxf(acc.x, v[u].x);
            acc.y = fmaxf(acc.y, v[u].y);
            acc.z = fmaxf(acc.z, v[u].z);
            acc.w = fmaxf(acc.w, v[u].w);
        }
    }

    ((float4*)out)[(size_t)cell * (FC / 4) + lane] = acc;
}

extern "C" void kernel_launch(void* const* d_in, const int* in_sizes, int n_in,
                              void* d_out, int out_size, void* d_ws, size_t ws_size,
                              hipStream_t stream) {
    const float* feat = (const float*)d_in[0];   // (1,64,64,256)
    const float* rois = (const float*)d_in[1];   // (1,256,4)
    float* out = (float*)d_out;                  // (1,256,7,7,256)

    const int total_threads = NROI * PP * PP * 64;  // one wave per cell
    const int block = 256;
    const int grid = (total_threads + block - 1) / block;  // 3136
    roi_pool_kernel<<<grid, block, 0, stream>>>(feat, rois, out);
}

// Round 5
// 67.664 us; speedup vs baseline: 1.0094x; 1.0094x over previous
//
#include <hip/hip_runtime.h>
#include <math.h>

// Problem constants (from reference)
#define FH 64    // feature map H (axis indexed by x)
#define FW 64    // feature map W (axis indexed by y)
#define FC 256   // channels
#define PP 7     // pool output dim
#define NROI 256
#define CHMAX 16 // max loads per memory round

__device__ __forceinline__ float4 fmax4(float4 a, float4 b) {
    return make_float4(fmaxf(a.x, b.x), fmaxf(a.y, b.y),
                       fmaxf(a.z, b.z), fmaxf(a.w, b.w));
}

// CHK independent loads (offsets precomputed, tail slots duplicated) issued
// back-to-back, then one reduction pass. No address math between loads.
template <int CHK>
__device__ __forceinline__ float4 batch_max(const float4* __restrict__ base,
                                            const int* off, float4 acc) {
    float4 v[CHK];
#pragma unroll
    for (int u = 0; u < CHK; ++u) v[u] = base[off[u]];
#pragma unroll
    for (int u = 0; u < CHK; ++u) acc = fmax4(acc, v[u]);
    return acc;
}

// One 64-lane wave per output cell (r,i,j); lane = 4-channel group (float4),
// 1KB coalesced per load. All walk state is wave-uniform (scalarized via
// readfirstlane on cell -> roi fetch is s_load, bin math on SALU).
// Input domain (0<=x1<x2<=1) makes the reference's clip() a no-op (max
// visited coord = ceil(x2*64)-1 <= 63), so clamps are dropped.
// __launch_bounds__(256,2): VGPR cap 256 so a full load batch stays in
// registers -> real memory-level parallelism instead of reg-recycled waits.
__global__ __launch_bounds__(256, 2) void roi_pool_kernel(
        const float* __restrict__ feat,   // (FH, FW, FC)
        const float* __restrict__ rois,   // (NROI, 4): x1,y1,x2,y2
        float* __restrict__ out)          // (NROI, PP, PP, FC)
{
    const int lane = threadIdx.x & 63;
    int cell = (blockIdx.x * blockDim.x + threadIdx.x) >> 6;
    cell = __builtin_amdgcn_readfirstlane(cell);   // wave-uniform -> SGPR

    const int j = cell % PP;
    const int t = cell / PP;
    const int i = t % PP;
    const int r = t / PP;

    const float4 roi = ((const float4*)rois)[r];   // uniform -> s_load_dwordx4

    int xlo = (int)floorf(roi.x * (float)FH);
    int xspan = (int)ceilf(roi.z * (float)FH) - xlo;
    xspan = xspan > 1 ? xspan : 1;
    int ylo = (int)floorf(roi.y * (float)FW);
    int yspan = (int)ceilf(roi.w * (float)FW) - ylo;
    yspan = yspan > 1 ? yspan : 1;

    // bin bounds (exact reference math; nonneg -> int div == floor)
    const int xs = xlo + (i * xspan) / PP;
    int xlen = (xlo + ((i + 1) * xspan + (PP - 1)) / PP) - xs;
    xlen = xlen > 1 ? xlen : 1;
    const int ys = ylo + (j * yspan) / PP;
    int ylen = (ylo + ((j + 1) * yspan + (PP - 1)) / PP) - ys;
    ylen = ylen > 1 ? ylen : 1;

    const float4* __restrict__ p =
        (const float4*)feat + (size_t)(xs * FW + ys) * (FC / 4) + lane;
    const int dnext = (FC / 4);                    // +1 pixel along y
    const int dwrap = (FW - ylen + 1) * (FC / 4);  // wrap to next x row

    float4 acc = make_float4(-INFINITY, -INFINITY, -INFINITY, -INFINITY);

    const int n = xlen * ylen;   // wave-uniform window size (<= 36 here)
    int cur = 0;                 // running offset (float4 units), uniform
    int sy = 0;                  // position within current y-run

    for (int q = 0; q < n; q += CHMAX) {
        const int m = n - q;     // pixels left in this round (uniform)
        int off[CHMAX];
        off[0] = cur;
#pragma unroll
        for (int u = 1; u < CHMAX; ++u) {
            if (u < m) {         // advance only while valid; else duplicate
                int wrap = (sy + 1 == ylen);
                cur += wrap ? dwrap : dnext;
                sy = wrap ? 0 : sy + 1;
            }
            off[u] = cur;
        }
        // tiered single-round batches: minimal tail duplication
        if (m <= 4)      acc = batch_max<4>(p, off, acc);
        else if (m <= 8) acc = batch_max<8>(p, off, acc);
        else             acc = batch_max<CHMAX>(p, off, acc);

        if (q + CHMAX < n) {     // step into next round's first pixel
            int wrap = (sy + 1 == ylen);
            cur += wrap ? dwrap : dnext;
            sy = wrap ? 0 : sy + 1;
        }
    }

    ((float4*)out)[(size_t)cell * (FC / 4) + lane] = acc;
}

extern "C" void kernel_launch(void* const* d_in, const int* in_sizes, int n_in,
                              void* d_out, int out_size, void* d_ws, size_t ws_size,
                              hipStream_t stream) {
    const float* feat = (const float*)d_in[0];   // (1,64,64,256)
    const float* rois = (const float*)d_in[1];   // (1,256,4)
    float* out = (float*)d_out;                  // (1,256,7,7,256)

    const int total_threads = NROI * PP * PP * 64;  // one wave per cell
    const int block = 256;
    const int grid = (total_threads + block - 1) / block;  // 3136 exact
    roi_pool_kernel<<<grid, block, 0, stream>>>(feat, rois, out);
}